// Round 2
// baseline (3530.684 us; speedup 1.0000x reference)
//
#include <hip/hip_runtime.h>

typedef unsigned short u16;
typedef __attribute__((ext_vector_type(8))) short short8;
typedef __attribute__((ext_vector_type(4))) float f32x4;

#define NB 1024
#define TT 64
#define CC 768
#define HH 12
#define HD 64
#define MLP 3072

__device__ __forceinline__ float b2f(u16 u) {
    return __uint_as_float(((unsigned)u) << 16);
}
__device__ __forceinline__ u16 f2b(float f) {
    unsigned u = __float_as_uint(f);
    unsigned r = (u + 0x7fff + ((u >> 16) & 1)) >> 16;
    return (u16)r;
}

__device__ __forceinline__ void block_reduce2(float& a, float& b, float* rbuf, int tid) {
#pragma unroll
    for (int off = 32; off > 0; off >>= 1) {
        a += __shfl_down(a, off, 64);
        b += __shfl_down(b, off, 64);
    }
    int wid = tid >> 6, lane = tid & 63;
    if (lane == 0) { rbuf[wid] = a; rbuf[wid + 4] = b; }
    __syncthreads();
    a = rbuf[0] + rbuf[1] + rbuf[2] + rbuf[3];
    b = rbuf[4] + rbuf[5] + rbuf[6] + rbuf[7];
    __syncthreads();
}

// ---------------- init / misc kernels ----------------

__global__ __launch_bounds__(256) void init_x_kernel(const float* __restrict__ cls, float* __restrict__ x) {
    int idx = blockIdx.x * 256 + threadIdx.x;  // < 786432
    x[idx] = cls[idx % CC];
}

__global__ __launch_bounds__(256) void store_out_kernel(const float* __restrict__ x, float* __restrict__ out) {
    int idx = blockIdx.x * 256 + threadIdx.x;
    out[idx] = x[idx];
}

// wkT[l][i][c] = wk[l][c][i], fp32 -> bf16
__global__ __launch_bounds__(256) void transpose_k_kernel(const float* __restrict__ wk, u16* __restrict__ wkT) {
    __shared__ float tile[32][33];
    int l = blockIdx.z;
    const float* src = wk + (long)l * (CC * CC);
    u16* dst = wkT + (long)l * (CC * CC);
    int i0 = blockIdx.x * 32, c0 = blockIdx.y * 32;
    int tx = threadIdx.x & 31, ty = threadIdx.x >> 5;  // ty 0..7
#pragma unroll
    for (int u = 0; u < 4; ++u)
        tile[ty + 8 * u][tx] = src[(long)(c0 + ty + 8 * u) * CC + i0 + tx];
    __syncthreads();
#pragma unroll
    for (int u = 0; u < 4; ++u)
        dst[(long)(i0 + ty + 8 * u) * CC + c0 + tx] = f2b(tile[tx][ty + 8 * u]);
}

// LN over C=768 of fp32 x -> bf16 out, with fp32 gamma/beta
__global__ __launch_bounds__(256) void ln_kernel(const float* __restrict__ x, const float* __restrict__ g,
                                                 const float* __restrict__ b, u16* __restrict__ out) {
    __shared__ float rbuf[8];
    int n = blockIdx.x, tid = threadIdx.x;
    const float* xr = x + (long)n * CC;
    float v0 = xr[tid], v1 = xr[tid + 256], v2 = xr[tid + 512];
    float s = v0 + v1 + v2, ss = v0 * v0 + v1 * v1 + v2 * v2;
    block_reduce2(s, ss, rbuf, tid);
    float mu = s * (1.0f / 768.0f);
    float rs = rsqrtf(ss * (1.0f / 768.0f) - mu * mu + 1e-5f);
    u16* orow = out + (long)n * CC;
    orow[tid]       = f2b((v0 - mu) * rs * g[tid]       + b[tid]);
    orow[tid + 256] = f2b((v1 - mu) * rs * g[tid + 256] + b[tid + 256]);
    orow[tid + 512] = f2b((v2 - mu) * rs * g[tid + 512] + b[tid + 512]);
}

// qb[n*12+h] = sum_d q[n, h*64+d] * bk[h*64+d]
__global__ __launch_bounds__(256) void qb_kernel(const u16* __restrict__ q, const float* __restrict__ bk,
                                                 float* __restrict__ qb) {
    int lane = threadIdx.x & 63;
    int idx = blockIdx.x * 4 + (threadIdx.x >> 6);  // n*12+h
    int n = idx / 12, h = idx - n * 12;
    float v = b2f(q[(long)n * CC + h * 64 + lane]) * bk[h * 64 + lane];
#pragma unroll
    for (int off = 32; off > 0; off >>= 1) v += __shfl_down(v, off, 64);
    if (lane == 0) qb[idx] = v;
}

// ---------------- generic MFMA GEMM (64x64 tile, K-step 32) ----------------
// A is always bf16 (our intermediates). B is fp32 input (B_F32=1) or bf16 ws (B_F32=0).
// C[m,n] = sum_k A[m,k]*B[k,n] (+bias[n]) (+gelu) ; out bf16 store or fp32 +=
template <int ACC_F32, int GELU, int HAS_BIAS, int B_F32>
__global__ __launch_bounds__(256) void gemm_kernel(const u16* __restrict__ A, int lda, long a_zoff,
                                                   const void* __restrict__ Bv, int ldb, long b_zoff,
                                                   void* __restrict__ Cout, int ldc, long c_zoff,
                                                   const float* __restrict__ bias, long bias_zoff,
                                                   int K) {
    __shared__ u16 As[64 * 40];
    __shared__ u16 Bs[64 * 40];
    const int tid = threadIdx.x;
    const int z = blockIdx.z;
    A += (long)z * a_zoff;
    const float* Bf = B_F32 ? ((const float*)Bv + (long)z * b_zoff) : nullptr;
    const u16* Bh = B_F32 ? nullptr : ((const u16*)Bv + (long)z * b_zoff);
    const float* bias_p = HAS_BIAS ? bias + (long)z * bias_zoff : nullptr;
    const long c_base = (long)z * c_zoff;
    const int m0 = blockIdx.y * 64;
    const int n0 = blockIdx.x * 64;

    const int am = tid >> 2;          // 0..63 row
    const int ak = (tid & 3) * 8;     // k group
    const int bn = tid & 63;          // col
    const int bk = (tid >> 6) * 8;    // k group

    const int lane = tid & 63;
    const int wid = tid >> 6;
    const int wm = (wid >> 1) * 32, wn = (wid & 1) * 32;
    const int l15 = lane & 15, q4 = lane >> 4;

    f32x4 acc[2][2] = {};

    for (int k0 = 0; k0 < K; k0 += 32) {
        int4 av = *(const int4*)(A + (long)(m0 + am) * lda + k0 + ak);
        unsigned bv0, bv1, bv2, bv3;
        if (B_F32) {
            const float* bp = Bf + (long)(k0 + bk) * ldb + n0 + bn;
            u16 e0 = f2b(bp[0]);
            u16 e1 = f2b(bp[(long)ldb]);
            u16 e2 = f2b(bp[(long)ldb * 2]);
            u16 e3 = f2b(bp[(long)ldb * 3]);
            u16 e4 = f2b(bp[(long)ldb * 4]);
            u16 e5 = f2b(bp[(long)ldb * 5]);
            u16 e6 = f2b(bp[(long)ldb * 6]);
            u16 e7 = f2b(bp[(long)ldb * 7]);
            bv0 = (unsigned)e0 | ((unsigned)e1 << 16); bv1 = (unsigned)e2 | ((unsigned)e3 << 16);
            bv2 = (unsigned)e4 | ((unsigned)e5 << 16); bv3 = (unsigned)e6 | ((unsigned)e7 << 16);
        } else {
            const u16* bp = Bh + (long)(k0 + bk) * ldb + n0 + bn;
            unsigned e0 = bp[0];
            unsigned e1 = bp[(long)ldb];
            unsigned e2 = bp[(long)ldb * 2];
            unsigned e3 = bp[(long)ldb * 3];
            unsigned e4 = bp[(long)ldb * 4];
            unsigned e5 = bp[(long)ldb * 5];
            unsigned e6 = bp[(long)ldb * 6];
            unsigned e7 = bp[(long)ldb * 7];
            bv0 = e0 | (e1 << 16); bv1 = e2 | (e3 << 16);
            bv2 = e4 | (e5 << 16); bv3 = e6 | (e7 << 16);
        }
        __syncthreads();
        *(int4*)(As + am * 40 + ak) = av;
        int4 bvv; bvv.x = (int)bv0; bvv.y = (int)bv1; bvv.z = (int)bv2; bvv.w = (int)bv3;
        *(int4*)(Bs + bn * 40 + bk) = bvv;  // Bs[n][k]
        __syncthreads();

        short8 a_f[2], b_f[2];
        a_f[0] = *(const short8*)(As + (wm + l15) * 40 + q4 * 8);
        a_f[1] = *(const short8*)(As + (wm + 16 + l15) * 40 + q4 * 8);
        b_f[0] = *(const short8*)(Bs + (wn + l15) * 40 + q4 * 8);
        b_f[1] = *(const short8*)(Bs + (wn + 16 + l15) * 40 + q4 * 8);
#pragma unroll
        for (int i = 0; i < 2; ++i)
#pragma unroll
            for (int j = 0; j < 2; ++j)
                acc[i][j] = __builtin_amdgcn_mfma_f32_16x16x32_bf16(a_f[i], b_f[j], acc[i][j], 0, 0, 0);
    }

    // epilogue: D[row=q4*4+r][col=l15] per 16x16 tile
#pragma unroll
    for (int i = 0; i < 2; ++i) {
#pragma unroll
        for (int j = 0; j < 2; ++j) {
            int row = m0 + wm + i * 16 + q4 * 4;
            int col = n0 + wn + j * 16 + l15;
            float bias_v = 0.f;
            if (HAS_BIAS) bias_v = bias_p[col];
#pragma unroll
            for (int r = 0; r < 4; ++r) {
                float v = acc[i][j][r] + bias_v;
                if (GELU) v = v / (1.0f + __expf(-1.702f * v));
                if (ACC_F32) {
                    float* Cf = (float*)Cout + c_base;
                    Cf[(long)(row + r) * ldc + col] += v;
                } else {
                    u16* Cb = (u16*)Cout + c_base;
                    Cb[(long)(row + r) * ldc + col] = f2b(v);
                }
            }
        }
    }
}

// ---------------- fused attention kernel (one block per sample) ----------------
// computes yn = LN3(in + dwconv(in) + cb + pe), aff[t,h]=scale*(yn.qproj+qb) masked,
// online softmax over t (chunks of 16), s[h,c] = sum_t p[t,h]*yn[t,c] (normalized)
__global__ __launch_bounds__(256) void attn_kernel(const float* __restrict__ inf, const int* __restrict__ mask,
                                                   const float* __restrict__ cw, const float* __restrict__ cb,
                                                   const float* __restrict__ pe, const float* __restrict__ g3,
                                                   const float* __restrict__ b3, const u16* __restrict__ qproj,
                                                   const float* __restrict__ qb, u16* __restrict__ s_out) {
    __shared__ u16 yn_s[16 * 776];
    __shared__ u16 qp_s[12 * 776];
    __shared__ float aff_s[16 * 13];
    __shared__ float qb_s[12], mh_s[12], lh_s[12], al_s[12];
    __shared__ float rbuf[8];

    const int tid = threadIdx.x;
    const int n = blockIdx.x;
    const long ibase = (long)n * (TT * CC);

    float cw0[3], cw1[3], cw2[3], cbv[3], gg[3], bb[3];
#pragma unroll
    for (int j = 0; j < 3; ++j) {
        int c = tid + 256 * j;
        cw0[j] = cw[c * 3 + 0];
        cw1[j] = cw[c * 3 + 1];
        cw2[j] = cw[c * 3 + 2];
        cbv[j] = cb[c];
        gg[j] = g3[c];
        bb[j] = b3[c];
    }
    // stage qproj[n] into LDS (padded rows of 776)
    for (int idx = tid * 4; idx < HH * CC; idx += 1024) {
        uint2 v = *(const uint2*)(qproj + (long)n * (HH * CC) + idx);
        int h = idx / CC, c = idx - h * CC;
        *(uint2*)(qp_s + h * 776 + c) = v;
    }
    if (tid < 12) { qb_s[tid] = qb[n * 12 + tid]; mh_s[tid] = -1e30f; lh_s[tid] = 0.f; }

    float s_acc[36];
#pragma unroll
    for (int j = 0; j < 36; ++j) s_acc[j] = 0.f;

    float pv[3], cv[3], nv[3];

    for (int tc = 0; tc < 4; ++tc) {
        const int t0 = tc * 16;
        // ---- phase A: compute 16 yn rows ----
#pragma unroll
        for (int j = 0; j < 3; ++j) {
            int c = tid + 256 * j;
            pv[j] = (t0 > 0) ? inf[ibase + (long)(t0 - 1) * CC + c] : 0.f;
            cv[j] = inf[ibase + (long)t0 * CC + c];
        }
        for (int it = 0; it < 16; ++it) {
            int t = t0 + it;
            float y[3];
            float s = 0.f, ss = 0.f;
#pragma unroll
            for (int j = 0; j < 3; ++j) {
                int c = tid + 256 * j;
                nv[j] = (t < 63) ? inf[ibase + (long)(t + 1) * CC + c] : 0.f;
                float yy = cv[j] + cw0[j] * pv[j] + cw1[j] * cv[j] + cw2[j] * nv[j] + cbv[j] +
                           pe[t * CC + c];
                y[j] = yy;
                s += yy;
                ss += yy * yy;
            }
            block_reduce2(s, ss, rbuf, tid);
            float mu = s * (1.0f / 768.0f);
            float rs = rsqrtf(ss * (1.0f / 768.0f) - mu * mu + 1e-5f);
#pragma unroll
            for (int j = 0; j < 3; ++j) {
                int c = tid + 256 * j;
                yn_s[it * 776 + c] = f2b((y[j] - mu) * rs * gg[j] + bb[j]);
                pv[j] = cv[j];
                cv[j] = nv[j];
            }
        }
        __syncthreads();
        // ---- phase B: aff[t,h] for this chunk ----
        if (tid < 192) {
            int t = tid / 12, h = tid - t * 12;
            const u16* yrow = yn_s + t * 776;
            const u16* qrow = qp_s + h * 776;
            float dot = 0.f;
#pragma unroll 8
            for (int c = 0; c < CC; c += 2) {
                unsigned ya = *(const unsigned*)(yrow + c);
                unsigned qa = *(const unsigned*)(qrow + c);
                dot = fmaf(__uint_as_float(ya << 16), __uint_as_float(qa << 16), dot);
                dot = fmaf(__uint_as_float(ya & 0xffff0000u), __uint_as_float(qa & 0xffff0000u), dot);
            }
            float a = 0.125f * (dot + qb_s[h]);
            if (mask[n * TT + t0 + t] == 0) a = -1e30f;
            aff_s[t * 13 + h] = a;
        }
        __syncthreads();
        // ---- phase C: online softmax update (12 head-leader threads) ----
        if (tid < 12) {
            int h = tid;
            float mold = mh_s[h];
            float mc = mold;
#pragma unroll
            for (int t = 0; t < 16; ++t) mc = fmaxf(mc, aff_s[t * 13 + h]);
            float al = __expf(mold - mc);
            float ls = 0.f;
#pragma unroll
            for (int t = 0; t < 16; ++t) {
                float p = __expf(aff_s[t * 13 + h] - mc);
                aff_s[t * 13 + h] = p;
                ls += p;
            }
            lh_s[h] = lh_s[h] * al + ls;
            mh_s[h] = mc;
            al_s[h] = al;
        }
        __syncthreads();
        // ---- phase D: accumulate s_acc ----
#pragma unroll
        for (int j = 0; j < 36; ++j) {
            int o = j * 256 + tid;
            int h = o / CC;
            int c = o - h * CC;
            float acc = s_acc[j] * al_s[h];
            const u16* yc = yn_s + c;
#pragma unroll
            for (int t = 0; t < 16; ++t)
                acc = fmaf(aff_s[t * 13 + h], b2f(yc[t * 776]), acc);
            s_acc[j] = acc;
        }
        __syncthreads();
    }
    // normalize and write s
#pragma unroll
    for (int j = 0; j < 36; ++j) {
        int o = j * 256 + tid;
        int h = o / CC;
        s_out[(long)n * (HH * CC) + o] = f2b(s_acc[j] / lh_s[h]);
    }
}

// ---------------- host ----------------

extern "C" void kernel_launch(void* const* d_in, const int* in_sizes, int n_in,
                              void* d_out, int out_size, void* d_ws, size_t ws_size,
                              hipStream_t stream) {
    const float* inf    = (const float*)d_in[0];
    const int* mask     = (const int*)d_in[1];
    const float* cls    = (const float*)d_in[2];
    const float* conv_w = (const float*)d_in[3];
    const float* conv_b = (const float*)d_in[4];
    const float* pos    = (const float*)d_in[5];
    const float* wq     = (const float*)d_in[6];
    const float* bq     = (const float*)d_in[7];
    const float* wk     = (const float*)d_in[8];
    const float* bk     = (const float*)d_in[9];
    const float* wv     = (const float*)d_in[10];
    const float* bv     = (const float*)d_in[11];
    const float* wo     = (const float*)d_in[12];
    const float* bo     = (const float*)d_in[13];
    const float* fc1w   = (const float*)d_in[14];
    const float* fc1b   = (const float*)d_in[15];
    const float* fc2w   = (const float*)d_in[16];
    const float* fc2b   = (const float*)d_in[17];
    const float* ln1g   = (const float*)d_in[18];
    const float* ln1b   = (const float*)d_in[19];
    const float* ln2g   = (const float*)d_in[20];
    const float* ln2b   = (const float*)d_in[21];
    const float* ln3g   = (const float*)d_in[22];
    const float* ln3b   = (const float*)d_in[23];

    char* ws = (char*)d_ws;
    float* x     = (float*)(ws + 0);             // 3,145,728 B
    u16* xn      = (u16*)(ws + 3145728);         // 1,572,864
    u16* qbuf    = (u16*)(ws + 4718592);         // 1,572,864
    float* qb    = (float*)(ws + 6291456);       // 49,152
    u16* qproj   = (u16*)(ws + 6340608);         // 18,874,368
    u16* sbuf    = (u16*)(ws + 25214976);        // 18,874,368
    u16* mix     = (u16*)(ws + 44089344);        // 1,572,864
    u16* g       = (u16*)(ws + 45662208);        // 6,291,456
    u16* wkT     = (u16*)(ws + 51953664);        // 4,718,592  -> total 56,672,256 B

    const int LCC = CC * CC;       // 589824
    const int LCM = CC * MLP;      // 2359296

    init_x_kernel<<<dim3(3072), dim3(256), 0, stream>>>(cls, x);
    transpose_k_kernel<<<dim3(24, 24, 4), dim3(256), 0, stream>>>(wk, wkT);

    for (int l = 0; l < 4; ++l) {
        const float* wq_l = wq + (long)l * LCC;
        const float* wv_l = wv + (long)l * LCC;
        const float* wo_l = wo + (long)l * LCC;
        const u16* wkT_l = wkT + (long)l * LCC;
        const float* fc1w_l = fc1w + (long)l * LCM;
        const float* fc2w_l = fc2w + (long)l * LCM;

        // qn = LN1(x); q = qn@wq + bq
        ln_kernel<<<dim3(1024), dim3(256), 0, stream>>>(x, ln1g + l * CC, ln1b + l * CC, xn);
        gemm_kernel<0, 0, 1, 1><<<dim3(12, 16, 1), dim3(256), 0, stream>>>(
            xn, CC, 0, wq_l, CC, 0, qbuf, CC, 0, bq + l * CC, 0, CC);
        // qb[n,h]
        qb_kernel<<<dim3(3072), dim3(256), 0, stream>>>(qbuf, bk + l * CC, qb);
        // qproj[n,h,c] = q_h @ wk_h^T   (z = head)
        gemm_kernel<0, 0, 0, 0><<<dim3(12, 16, 12), dim3(256), 0, stream>>>(
            qbuf, CC, 64, wkT_l, CC, 64 * CC, qproj, HH * CC, CC, nullptr, 0, 64);
        // fused conv+LN3+attention -> s[n,h,c]
        attn_kernel<<<dim3(1024), dim3(256), 0, stream>>>(
            inf, mask, conv_w + l * CC * 3, conv_b + l * CC, pos + (long)l * TT * CC,
            ln3g + l * CC, ln3b + l * CC, qproj, qb, sbuf);
        // mix[n, h*64+d] = s[n,h,:] @ wv_h + bv_h   (z = head)
        gemm_kernel<0, 0, 1, 1><<<dim3(1, 16, 12), dim3(256), 0, stream>>>(
            sbuf, HH * CC, CC, wv_l, CC, 64, mix, CC, 64, bv + l * CC, 64, CC);
        // x += mix @ wo + bo
        gemm_kernel<1, 0, 1, 1><<<dim3(12, 16, 1), dim3(256), 0, stream>>>(
            mix, CC, 0, wo_l, CC, 0, x, CC, 0, bo + l * CC, 0, CC);
        // MLP
        ln_kernel<<<dim3(1024), dim3(256), 0, stream>>>(x, ln2g + l * CC, ln2b + l * CC, xn);
        gemm_kernel<0, 1, 1, 1><<<dim3(48, 16, 1), dim3(256), 0, stream>>>(
            xn, CC, 0, fc1w_l, MLP, 0, g, MLP, 0, fc1b + l * MLP, 0, CC);
        gemm_kernel<1, 0, 1, 1><<<dim3(12, 16, 1), dim3(256), 0, stream>>>(
            g, MLP, 0, fc2w_l, CC, 0, x, CC, 0, fc2b + l * CC, 0, MLP);
    }

    store_out_kernel<<<dim3(3072), dim3(256), 0, stream>>>(x, (float*)d_out);
}

// Round 3
// 1602.754 us; speedup vs baseline: 2.2029x; 2.2029x over previous
//
#include <hip/hip_runtime.h>

typedef unsigned short u16;
typedef __attribute__((ext_vector_type(8))) short short8;
typedef __attribute__((ext_vector_type(4))) float f32x4;

#define NB 1024
#define TT 64
#define CC 768
#define HH 12
#define HD 64
#define MLP 3072

__device__ __forceinline__ float b2f(u16 u) {
    return __uint_as_float(((unsigned)u) << 16);
}
__device__ __forceinline__ u16 f2b(float f) {
    unsigned u = __float_as_uint(f);
    unsigned r = (u + 0x7fff + ((u >> 16) & 1)) >> 16;
    return (u16)r;
}

__device__ __forceinline__ void block_reduce2(float& a, float& b, float* rbuf, int tid) {
#pragma unroll
    for (int off = 32; off > 0; off >>= 1) {
        a += __shfl_down(a, off, 64);
        b += __shfl_down(b, off, 64);
    }
    int wid = tid >> 6, lane = tid & 63;
    if (lane == 0) { rbuf[wid] = a; rbuf[wid + 4] = b; }
    __syncthreads();
    a = rbuf[0] + rbuf[1] + rbuf[2] + rbuf[3];
    b = rbuf[4] + rbuf[5] + rbuf[6] + rbuf[7];
    __syncthreads();
}

// ---------------- init / misc kernels ----------------

__global__ __launch_bounds__(256) void init_x_kernel(const float* __restrict__ cls, float* __restrict__ x) {
    int idx = blockIdx.x * 256 + threadIdx.x;  // < 786432
    x[idx] = cls[idx % CC];
}

__global__ __launch_bounds__(256) void store_out_kernel(const float* __restrict__ x, float* __restrict__ out) {
    int idx = blockIdx.x * 256 + threadIdx.x;
    out[idx] = x[idx];
}

// wkT[l][i][c] = wk[l][c][i], fp32 -> bf16
__global__ __launch_bounds__(256) void transpose_k_kernel(const float* __restrict__ wk, u16* __restrict__ wkT) {
    __shared__ float tile[32][33];
    int l = blockIdx.z;
    const float* src = wk + (long)l * (CC * CC);
    u16* dst = wkT + (long)l * (CC * CC);
    int i0 = blockIdx.x * 32, c0 = blockIdx.y * 32;
    int tx = threadIdx.x & 31, ty = threadIdx.x >> 5;  // ty 0..7
#pragma unroll
    for (int u = 0; u < 4; ++u)
        tile[ty + 8 * u][tx] = src[(long)(c0 + ty + 8 * u) * CC + i0 + tx];
    __syncthreads();
#pragma unroll
    for (int u = 0; u < 4; ++u)
        dst[(long)(i0 + ty + 8 * u) * CC + c0 + tx] = f2b(tile[tx][ty + 8 * u]);
}

// LN over C=768 of fp32 x -> bf16 out, with fp32 gamma/beta
__global__ __launch_bounds__(256) void ln_kernel(const float* __restrict__ x, const float* __restrict__ g,
                                                 const float* __restrict__ b, u16* __restrict__ out) {
    __shared__ float rbuf[8];
    int n = blockIdx.x, tid = threadIdx.x;
    const float* xr = x + (long)n * CC;
    float v0 = xr[tid], v1 = xr[tid + 256], v2 = xr[tid + 512];
    float s = v0 + v1 + v2, ss = v0 * v0 + v1 * v1 + v2 * v2;
    block_reduce2(s, ss, rbuf, tid);
    float mu = s * (1.0f / 768.0f);
    float rs = rsqrtf(ss * (1.0f / 768.0f) - mu * mu + 1e-5f);
    u16* orow = out + (long)n * CC;
    orow[tid]       = f2b((v0 - mu) * rs * g[tid]       + b[tid]);
    orow[tid + 256] = f2b((v1 - mu) * rs * g[tid + 256] + b[tid + 256]);
    orow[tid + 512] = f2b((v2 - mu) * rs * g[tid + 512] + b[tid + 512]);
}

// qb[n*12+h] = sum_d q[n, h*64+d] * bk[h*64+d]
__global__ __launch_bounds__(256) void qb_kernel(const u16* __restrict__ q, const float* __restrict__ bk,
                                                 float* __restrict__ qb) {
    int lane = threadIdx.x & 63;
    int idx = blockIdx.x * 4 + (threadIdx.x >> 6);  // n*12+h
    int n = idx / 12, h = idx - n * 12;
    float v = b2f(q[(long)n * CC + h * 64 + lane]) * bk[h * 64 + lane];
#pragma unroll
    for (int off = 32; off > 0; off >>= 1) v += __shfl_down(v, off, 64);
    if (lane == 0) qb[idx] = v;
}

// ---------------- generic MFMA GEMM (64x64 tile, K-step 32) ----------------
template <int ACC_F32, int GELU, int HAS_BIAS, int B_F32>
__global__ __launch_bounds__(256) void gemm_kernel(const u16* __restrict__ A, int lda, long a_zoff,
                                                   const void* __restrict__ Bv, int ldb, long b_zoff,
                                                   void* __restrict__ Cout, int ldc, long c_zoff,
                                                   const float* __restrict__ bias, long bias_zoff,
                                                   int K) {
    __shared__ u16 As[64 * 40];
    __shared__ u16 Bs[64 * 40];
    const int tid = threadIdx.x;
    const int z = blockIdx.z;
    A += (long)z * a_zoff;
    const float* Bf = B_F32 ? ((const float*)Bv + (long)z * b_zoff) : nullptr;
    const u16* Bh = B_F32 ? nullptr : ((const u16*)Bv + (long)z * b_zoff);
    const float* bias_p = HAS_BIAS ? bias + (long)z * bias_zoff : nullptr;
    const long c_base = (long)z * c_zoff;
    const int m0 = blockIdx.y * 64;
    const int n0 = blockIdx.x * 64;

    const int am = tid >> 2;
    const int ak = (tid & 3) * 8;
    const int bn = tid & 63;
    const int bk = (tid >> 6) * 8;

    const int lane = tid & 63;
    const int wid = tid >> 6;
    const int wm = (wid >> 1) * 32, wn = (wid & 1) * 32;
    const int l15 = lane & 15, q4 = lane >> 4;

    f32x4 acc[2][2] = {};

    for (int k0 = 0; k0 < K; k0 += 32) {
        int4 av = *(const int4*)(A + (long)(m0 + am) * lda + k0 + ak);
        unsigned bv0, bv1, bv2, bv3;
        if (B_F32) {
            const float* bp = Bf + (long)(k0 + bk) * ldb + n0 + bn;
            u16 e0 = f2b(bp[0]);
            u16 e1 = f2b(bp[(long)ldb]);
            u16 e2 = f2b(bp[(long)ldb * 2]);
            u16 e3 = f2b(bp[(long)ldb * 3]);
            u16 e4 = f2b(bp[(long)ldb * 4]);
            u16 e5 = f2b(bp[(long)ldb * 5]);
            u16 e6 = f2b(bp[(long)ldb * 6]);
            u16 e7 = f2b(bp[(long)ldb * 7]);
            bv0 = (unsigned)e0 | ((unsigned)e1 << 16); bv1 = (unsigned)e2 | ((unsigned)e3 << 16);
            bv2 = (unsigned)e4 | ((unsigned)e5 << 16); bv3 = (unsigned)e6 | ((unsigned)e7 << 16);
        } else {
            const u16* bp = Bh + (long)(k0 + bk) * ldb + n0 + bn;
            unsigned e0 = bp[0];
            unsigned e1 = bp[(long)ldb];
            unsigned e2 = bp[(long)ldb * 2];
            unsigned e3 = bp[(long)ldb * 3];
            unsigned e4 = bp[(long)ldb * 4];
            unsigned e5 = bp[(long)ldb * 5];
            unsigned e6 = bp[(long)ldb * 6];
            unsigned e7 = bp[(long)ldb * 7];
            bv0 = e0 | (e1 << 16); bv1 = e2 | (e3 << 16);
            bv2 = e4 | (e5 << 16); bv3 = e6 | (e7 << 16);
        }
        __syncthreads();
        *(int4*)(As + am * 40 + ak) = av;
        int4 bvv; bvv.x = (int)bv0; bvv.y = (int)bv1; bvv.z = (int)bv2; bvv.w = (int)bv3;
        *(int4*)(Bs + bn * 40 + bk) = bvv;  // Bs[n][k]
        __syncthreads();

        short8 a_f[2], b_f[2];
        a_f[0] = *(const short8*)(As + (wm + l15) * 40 + q4 * 8);
        a_f[1] = *(const short8*)(As + (wm + 16 + l15) * 40 + q4 * 8);
        b_f[0] = *(const short8*)(Bs + (wn + l15) * 40 + q4 * 8);
        b_f[1] = *(const short8*)(Bs + (wn + 16 + l15) * 40 + q4 * 8);
#pragma unroll
        for (int i = 0; i < 2; ++i)
#pragma unroll
            for (int j = 0; j < 2; ++j)
                acc[i][j] = __builtin_amdgcn_mfma_f32_16x16x32_bf16(a_f[i], b_f[j], acc[i][j], 0, 0, 0);
    }

#pragma unroll
    for (int i = 0; i < 2; ++i) {
#pragma unroll
        for (int j = 0; j < 2; ++j) {
            int row = m0 + wm + i * 16 + q4 * 4;
            int col = n0 + wn + j * 16 + l15;
            float bias_v = 0.f;
            if (HAS_BIAS) bias_v = bias_p[col];
#pragma unroll
            for (int r = 0; r < 4; ++r) {
                float v = acc[i][j][r] + bias_v;
                if (GELU) v = v / (1.0f + __expf(-1.702f * v));
                if (ACC_F32) {
                    float* Cf = (float*)Cout + c_base;
                    Cf[(long)(row + r) * ldc + col] += v;
                } else {
                    u16* Cb = (u16*)Cout + c_base;
                    Cb[(long)(row + r) * ldc + col] = f2b(v);
                }
            }
        }
    }
}

// ---------------- fused attention kernel v2 (one block per sample) ----------------
// Per chunk of 16 t-rows:
//   phase A: each wave LNs 4 rows (conv+pe+residual) with wave-only reductions -> yn_s
//   phase B: wave 0 computes aff(16x12) = yn @ qp^T via MFMA
//   phase C: 12 threads do online-softmax update (m,l,alpha; p stored in aff_s)
//   phase D: all waves: sacc = sacc*alpha + p^T @ yn via MFMA (K zero-padded to 32)
__global__ __launch_bounds__(256, 2) void attn_kernel(const float* __restrict__ inf, const int* __restrict__ mask,
                                                      const float* __restrict__ cw, const float* __restrict__ cb,
                                                      const float* __restrict__ pe, const float* __restrict__ g3,
                                                      const float* __restrict__ b3, const u16* __restrict__ qproj,
                                                      const float* __restrict__ qb, u16* __restrict__ s_out) {
    __shared__ u16 yn_s[16 * 776];    // 24832 B
    __shared__ u16 qp_s[16 * 776];    // 24832 B (rows 12..15 uninit, only read into discarded lanes)
    __shared__ float aff_s[16 * 13];  // 832 B
    __shared__ float qb_s[12];
    __shared__ float mh_s[16], lh_s[16], al_s[16];
    __shared__ int msk_s[64];

    const int tid = threadIdx.x;
    const int lane = tid & 63;
    const int wid = tid >> 6;
    const int l15 = lane & 15, q4 = lane >> 4;
    const int n = blockIdx.x;
    const long ibase = (long)n * (TT * CC);
    const int c0 = lane * 4;  // channels c0+256j+q, j=0..2, q=0..3

    // stage qproj[n] (12 rows of 768 bf16) into qp_s (776-stride)
    for (int idx = tid * 8; idx < HH * CC; idx += 256 * 8) {
        uint4 v = *(const uint4*)(qproj + (long)n * (HH * CC) + idx);
        int h = idx / CC, c = idx - h * CC;
        *(uint4*)(qp_s + h * 776 + c) = v;
    }
    if (tid < 12) qb_s[tid] = qb[n * 12 + tid];
    if (tid < 16) { mh_s[tid] = -1e30f; lh_s[tid] = 0.f; al_s[tid] = 1.f; }
    if (tid < 64) msk_s[tid] = mask[n * TT + tid];

    // per-thread conv/LN constants for its 12 channels
    float cw0a[12], cw1a[12], cw2a[12], cba[12], ga[12], ba[12];
#pragma unroll
    for (int j = 0; j < 3; ++j) {
        int c = c0 + 256 * j;
        *(float4*)(cba + 4 * j) = *(const float4*)(cb + c);
        *(float4*)(ga + 4 * j) = *(const float4*)(g3 + c);
        *(float4*)(ba + 4 * j) = *(const float4*)(b3 + c);
#pragma unroll
        for (int q = 0; q < 4; ++q) {
            cw0a[j * 4 + q] = cw[(c + q) * 3 + 0];
            cw1a[j * 4 + q] = cw[(c + q) * 3 + 1];
            cw2a[j * 4 + q] = cw[(c + q) * 3 + 2];
        }
    }

    f32x4 sacc[12] = {};  // s accumulator: h = q4*4+r (rows), c = (wid*12+jt)*16 + l15

    for (int tc = 0; tc < 4; ++tc) {
        const int t0 = tc * 16 + wid * 4;
        // ---- phase A: 4 rows per wave, wave-level reductions only ----
        float pva[12], cva[12], nva[12];
#pragma unroll
        for (int j = 0; j < 3; ++j) {
            int c = c0 + 256 * j;
            if (t0 > 0)
                *(float4*)(pva + 4 * j) = *(const float4*)(inf + ibase + (long)(t0 - 1) * CC + c);
            else
                *(float4*)(pva + 4 * j) = make_float4(0.f, 0.f, 0.f, 0.f);
            *(float4*)(cva + 4 * j) = *(const float4*)(inf + ibase + (long)t0 * CC + c);
        }
#pragma unroll
        for (int r = 0; r < 4; ++r) {
            const int t = t0 + r;
#pragma unroll
            for (int j = 0; j < 3; ++j) {
                int c = c0 + 256 * j;
                if (t < 63)
                    *(float4*)(nva + 4 * j) = *(const float4*)(inf + ibase + (long)(t + 1) * CC + c);
                else
                    *(float4*)(nva + 4 * j) = make_float4(0.f, 0.f, 0.f, 0.f);
            }
            float pev[12];
#pragma unroll
            for (int j = 0; j < 3; ++j)
                *(float4*)(pev + 4 * j) = *(const float4*)(pe + (long)t * CC + c0 + 256 * j);
            float y[12];
            float sm = 0.f, sq = 0.f;
#pragma unroll
            for (int q = 0; q < 12; ++q) {
                float yy = cva[q] + cw0a[q] * pva[q] + cw1a[q] * cva[q] + cw2a[q] * nva[q] + cba[q] + pev[q];
                y[q] = yy;
                sm += yy;
                sq += yy * yy;
            }
#pragma unroll
            for (int off = 32; off > 0; off >>= 1) {
                sm += __shfl_xor(sm, off, 64);
                sq += __shfl_xor(sq, off, 64);
            }
            float mu = sm * (1.0f / 768.0f);
            float rs = rsqrtf(sq * (1.0f / 768.0f) - mu * mu + 1e-5f);
#pragma unroll
            for (int j = 0; j < 3; ++j) {
                int c = c0 + 256 * j;
                unsigned w0 = (unsigned)f2b((y[j * 4 + 0] - mu) * rs * ga[j * 4 + 0] + ba[j * 4 + 0]) |
                              ((unsigned)f2b((y[j * 4 + 1] - mu) * rs * ga[j * 4 + 1] + ba[j * 4 + 1]) << 16);
                unsigned w1 = (unsigned)f2b((y[j * 4 + 2] - mu) * rs * ga[j * 4 + 2] + ba[j * 4 + 2]) |
                              ((unsigned)f2b((y[j * 4 + 3] - mu) * rs * ga[j * 4 + 3] + ba[j * 4 + 3]) << 16);
                *(uint2*)(yn_s + (wid * 4 + r) * 776 + c) = make_uint2(w0, w1);
            }
#pragma unroll
            for (int q = 0; q < 12; ++q) { pva[q] = cva[q]; cva[q] = nva[q]; }
        }
        __syncthreads();
        // ---- phase B: aff via MFMA (wave 0) ----
        if (wid == 0) {
            f32x4 aacc = {0.f, 0.f, 0.f, 0.f};
#pragma unroll 4
            for (int k0 = 0; k0 < CC; k0 += 32) {
                short8 a = *(const short8*)(yn_s + l15 * 776 + k0 + q4 * 8);
                short8 b = *(const short8*)(qp_s + l15 * 776 + k0 + q4 * 8);
                aacc = __builtin_amdgcn_mfma_f32_16x16x32_bf16(a, b, aacc, 0, 0, 0);
            }
            if (l15 < 12) {
#pragma unroll
                for (int r = 0; r < 4; ++r) {
                    int tl = q4 * 4 + r;
                    float a = 0.125f * (aacc[r] + qb_s[l15]);
                    if (msk_s[tc * 16 + tl] == 0) a = -1e30f;
                    aff_s[tl * 13 + l15] = a;
                }
            }
        }
        __syncthreads();
        // ---- phase C: online softmax update ----
        if (tid < 12) {
            int h = tid;
            float mold = mh_s[h], mc = mold;
#pragma unroll
            for (int tl = 0; tl < 16; ++tl) mc = fmaxf(mc, aff_s[tl * 13 + h]);
            float al = __expf(mold - mc);
            float ls = 0.f;
#pragma unroll
            for (int tl = 0; tl < 16; ++tl) {
                float p = __expf(aff_s[tl * 13 + h] - mc);
                aff_s[tl * 13 + h] = p;
                ls += p;
            }
            lh_s[h] = lh_s[h] * al + ls;
            mh_s[h] = mc;
            al_s[h] = al;
        }
        __syncthreads();
        // ---- phase D: sacc = sacc*alpha + p^T @ yn via MFMA ----
        short8 af;
#pragma unroll
        for (int jj = 0; jj < 8; ++jj) {
            int tl = q4 * 8 + jj;
            float p = (tl < 16 && l15 < 12) ? aff_s[tl * 13 + l15] : 0.f;
            af[jj] = (short)f2b(p);
        }
        float alph[4];
#pragma unroll
        for (int r = 0; r < 4; ++r) alph[r] = al_s[q4 * 4 + r];
#pragma unroll
        for (int jt = 0; jt < 12; ++jt) {
            int nn0 = (wid * 12 + jt) * 16;
            short8 bf;
#pragma unroll
            for (int jj = 0; jj < 8; ++jj) {
                int tl = q4 * 8 + jj;
                bf[jj] = (tl < 16) ? (short)yn_s[tl * 776 + nn0 + l15] : (short)0;
            }
            f32x4 a4 = sacc[jt];
#pragma unroll
            for (int r = 0; r < 4; ++r) a4[r] *= alph[r];
            sacc[jt] = __builtin_amdgcn_mfma_f32_16x16x32_bf16(af, bf, a4, 0, 0, 0);
        }
        __syncthreads();
    }
    // epilogue: normalize and write s[n, h*768+c]
    if (q4 < 3) {
#pragma unroll
        for (int jt = 0; jt < 12; ++jt) {
            int c = (wid * 12 + jt) * 16 + l15;
#pragma unroll
            for (int r = 0; r < 4; ++r) {
                int hh = q4 * 4 + r;
                s_out[(long)n * (HH * CC) + hh * CC + c] = f2b(sacc[jt][r] / lh_s[hh]);
            }
        }
    }
}

// ---------------- host ----------------

extern "C" void kernel_launch(void* const* d_in, const int* in_sizes, int n_in,
                              void* d_out, int out_size, void* d_ws, size_t ws_size,
                              hipStream_t stream) {
    const float* inf    = (const float*)d_in[0];
    const int* mask     = (const int*)d_in[1];
    const float* cls    = (const float*)d_in[2];
    const float* conv_w = (const float*)d_in[3];
    const float* conv_b = (const float*)d_in[4];
    const float* pos    = (const float*)d_in[5];
    const float* wq     = (const float*)d_in[6];
    const float* bq     = (const float*)d_in[7];
    const float* wk     = (const float*)d_in[8];
    const float* bk     = (const float*)d_in[9];
    const float* wv     = (const float*)d_in[10];
    const float* bv     = (const float*)d_in[11];
    const float* wo     = (const float*)d_in[12];
    const float* bo     = (const float*)d_in[13];
    const float* fc1w   = (const float*)d_in[14];
    const float* fc1b   = (const float*)d_in[15];
    const float* fc2w   = (const float*)d_in[16];
    const float* fc2b   = (const float*)d_in[17];
    const float* ln1g   = (const float*)d_in[18];
    const float* ln1b   = (const float*)d_in[19];
    const float* ln2g   = (const float*)d_in[20];
    const float* ln2b   = (const float*)d_in[21];
    const float* ln3g   = (const float*)d_in[22];
    const float* ln3b   = (const float*)d_in[23];

    char* ws = (char*)d_ws;
    float* x     = (float*)(ws + 0);             // 3,145,728 B
    u16* xn      = (u16*)(ws + 3145728);         // 1,572,864
    u16* qbuf    = (u16*)(ws + 4718592);         // 1,572,864
    float* qb    = (float*)(ws + 6291456);       // 49,152
    u16* qproj   = (u16*)(ws + 6340608);         // 18,874,368
    u16* sbuf    = (u16*)(ws + 25214976);        // 18,874,368
    u16* mix     = (u16*)(ws + 44089344);        // 1,572,864
    u16* g       = (u16*)(ws + 45662208);        // 6,291,456
    u16* wkT     = (u16*)(ws + 51953664);        // 4,718,592  -> total 56,672,256 B

    const int LCC = CC * CC;       // 589824
    const int LCM = CC * MLP;      // 2359296

    init_x_kernel<<<dim3(3072), dim3(256), 0, stream>>>(cls, x);
    transpose_k_kernel<<<dim3(24, 24, 4), dim3(256), 0, stream>>>(wk, wkT);

    for (int l = 0; l < 4; ++l) {
        const float* wq_l = wq + (long)l * LCC;
        const float* wv_l = wv + (long)l * LCC;
        const float* wo_l = wo + (long)l * LCC;
        const u16* wkT_l = wkT + (long)l * LCC;
        const float* fc1w_l = fc1w + (long)l * LCM;
        const float* fc2w_l = fc2w + (long)l * LCM;

        // qn = LN1(x); q = qn@wq + bq
        ln_kernel<<<dim3(1024), dim3(256), 0, stream>>>(x, ln1g + l * CC, ln1b + l * CC, xn);
        gemm_kernel<0, 0, 1, 1><<<dim3(12, 16, 1), dim3(256), 0, stream>>>(
            xn, CC, 0, wq_l, CC, 0, qbuf, CC, 0, bq + l * CC, 0, CC);
        // qb[n,h]
        qb_kernel<<<dim3(3072), dim3(256), 0, stream>>>(qbuf, bk + l * CC, qb);
        // qproj[n,h,c] = q_h @ wk_h^T   (z = head)
        gemm_kernel<0, 0, 0, 0><<<dim3(12, 16, 12), dim3(256), 0, stream>>>(
            qbuf, CC, 64, wkT_l, CC, 64 * CC, qproj, HH * CC, CC, nullptr, 0, 64);
        // fused conv+LN3+attention -> s[n,h,c]
        attn_kernel<<<dim3(1024), dim3(256), 0, stream>>>(
            inf, mask, conv_w + l * CC * 3, conv_b + l * CC, pos + (long)l * TT * CC,
            ln3g + l * CC, ln3b + l * CC, qproj, qb, sbuf);
        // mix[n, h*64+d] = s[n,h,:] @ wv_h + bv_h   (z = head)
        gemm_kernel<0, 0, 1, 1><<<dim3(1, 16, 12), dim3(256), 0, stream>>>(
            sbuf, HH * CC, CC, wv_l, CC, 64, mix, CC, 64, bv + l * CC, 64, CC);
        // x += mix @ wo + bo
        gemm_kernel<1, 0, 1, 1><<<dim3(12, 16, 1), dim3(256), 0, stream>>>(
            mix, CC, 0, wo_l, CC, 0, x, CC, 0, bo + l * CC, 0, CC);
        // MLP
        ln_kernel<<<dim3(1024), dim3(256), 0, stream>>>(x, ln2g + l * CC, ln2b + l * CC, xn);
        gemm_kernel<0, 1, 1, 1><<<dim3(48, 16, 1), dim3(256), 0, stream>>>(
            xn, CC, 0, fc1w_l, MLP, 0, g, MLP, 0, fc1b + l * MLP, 0, CC);
        gemm_kernel<1, 0, 1, 1><<<dim3(12, 16, 1), dim3(256), 0, stream>>>(
            g, MLP, 0, fc2w_l, CC, 0, x, CC, 0, fc2b + l * CC, 0, MLP);
    }

    store_out_kernel<<<dim3(3072), dim3(256), 0, stream>>>(x, (float*)d_out);
}